// Round 19
// baseline (346.580 us; speedup 1.0000x reference)
//
#include <hip/hip_runtime.h>

#define HID 10
#define TT  2048
#define BB  4096

typedef float f2 __attribute__((ext_vector_type(2)));

static __device__ __forceinline__ f2 pkmul(f2 a, f2 b) {
    f2 d; asm("v_pk_mul_f32 %0, %1, %2" : "=v"(d) : "v"(a), "v"(b)); return d;
}
static __device__ __forceinline__ f2 pkfma(f2 a, f2 b, f2 c) {
    f2 d; asm("v_pk_fma_f32 %0, %1, %2, %3" : "=v"(d) : "v"(a), "v"(b), "v"(c)); return d;
}

__device__ __forceinline__ float fast_tanh(float x) {
    // tanh(x) = 1 - 2/(exp2(x*2*log2e) + 1); saturates correctly at +-inf
    float e = exp2f(x * 2.885390081777926814f);
    float r = __builtin_amdgcn_rcpf(e + 1.0f);
    return fmaf(-2.0f, r, 1.0f);
}

// f32 -> bf16 bits, round-to-nearest-even (tanh-bounded: no NaN/Inf)
__device__ __forceinline__ unsigned short f2bf(float f) {
    unsigned u = __float_as_uint(f);
    return (unsigned short)((u + 0x7fffu + ((u >> 16) & 1u)) >> 16);
}
// unpack bf16x2 dword -> f2 {low, high}
__device__ __forceinline__ f2 unpk(unsigned d) {
    f2 r;
    r.x = __uint_as_float(d << 16);
    r.y = __uint_as_float(d & 0xffff0000u);
    return r;
}

#define PKDOT(ACC, W, H)                 \
    ACC = pkmul(W[0], H[0]);             \
    ACC = pkfma(W[1], H[1], ACC);        \
    ACC = pkfma(W[2], H[2], ACC);        \
    ACC = pkfma(W[3], H[3], ACC);        \
    ACC = pkfma(W[4], H[4], ACC);

// R18 structure (best: 277us) + bf16-packed h broadcasts (R15 mechanics):
// DS model (m134, shared per-CU): f32 readback b128+b128+b64 = 32 cyc ->
// bf16 b128+b32 = 18 cyc; per-CU DS 352 -> ~240 cyc/step. The u-dot on the
// OLD H0 keeps the readback latency off the chain (R18's trick; R15 lacked
// it and regressed). Half-wave phase permute {0,16,8,24} kills R18's 8
// counted conflict-cycles/block-step (conflicts are evaluated per 32-lane
// half-wave; R17's phases were half-disjoint and counted zero).
//   wave A: h0 recurrence + u(i-1) publish (one f32/lane into 16-slot ring);
//           lane10 publishes b_out.  DS: b16 write + b128 + b32 + b32 = 4.
//   wave B: h1 recurrence lag-9, rider lane10 (Wout on Whh1 dot) captures
//           out(j-1); 2-value lag-carry quad stores.  DS: 4.
__global__ void __launch_bounds__(128) rnn_kernel(
    const float* __restrict__ x,    const float* __restrict__ hs,
    const float* __restrict__ Wih0, const float* __restrict__ Whh0,
    const float* __restrict__ bih0, const float* __restrict__ bhh0,
    const float* __restrict__ Wih1, const float* __restrict__ Whh1,
    const float* __restrict__ bih1, const float* __restrict__ bhh1,
    const float* __restrict__ Wout, const float* __restrict__ boutp,
    float* __restrict__ out)
{
    const int tid  = threadIdx.x;
    const bool isA = tid < 64;
    const int lane = tid & 15;           // hidden unit slot
    const int grp  = (tid >> 4) & 3;     // row within block
    const int row  = blockIdx.x * 4 + grp;
    const bool act = (lane < HID);
    const bool ol  = (lane == HID);      // rider lane

    // stride 296 (mod 32 = 8); permuted bases give phases {0,16,8,24} so each
    // 32-lane half-wave's two groups are bank-disjoint. Regions per group:
    // u-ring [16][16] f32 @0, h0b 16*bf16 @float256, h1b 16*bf16 @float280.
    __shared__ float lds[4 * 296];
    const int pg = ((grp << 1) | (grp >> 1)) & 3;   // {0,2,1,3}
    float* base = &lds[pg * 296];
    float* up   = base + lane;
    unsigned short* h0b = (unsigned short*)(base + 256);
    unsigned short* h1b = (unsigned short*)(base + 280);

    const float* xrow = x   + (size_t)row * TT;
    float*       orow = out + (size_t)row * TT;

    // ---- role state ----
    f2 W0[5], W1[5], W2[5], H0[5], H1[5];
    float wih0i = 0.f, b0c = 0.f, ub = 0.f, obias = 0.f;
    float hown = 0.f;
    float4 xa = make_float4(0,0,0,0), xb = make_float4(0,0,0,0);
    float P1 = 0.f, P2 = 0.f;

    if (isA) {
        #pragma unroll
        for (int j = 0; j < 5; ++j) {
            W0[j] = act ? f2{Whh0[lane*HID + 2*j], Whh0[lane*HID + 2*j+1]}
                        : f2{0.f, 0.f};
            W1[j] = act ? f2{Wih1[lane*HID + 2*j], Wih1[lane*HID + 2*j+1]}
                        : f2{0.f, 0.f};
            H0[j] = f2{hs[row*HID + 2*j], hs[row*HID + 2*j+1]};
        }
        wih0i = act ? Wih0[lane] : 0.f;
        b0c   = act ? (bih0[lane] + bhh0[lane]) : 0.f;
        ub    = act ? (bih1[lane] + bhh1[lane]) : (ol ? boutp[0] : 0.f);
        hown  = act ? hs[row*HID + lane] : 0.f;
        xa = *(const float4*)(xrow);
        xb = *(const float4*)(xrow + 4);
    } else {
        #pragma unroll
        for (int j = 0; j < 5; ++j) {
            W2[j] = act ? f2{Whh1[lane*HID + 2*j], Whh1[lane*HID + 2*j+1]}
                  : (ol ? f2{Wout[2*j], Wout[2*j+1]} : f2{0.f, 0.f});
            H1[j] = f2{hs[BB*HID + row*HID + 2*j], hs[BB*HID + row*HID + 2*j+1]};
        }
        obias = ol ? boutp[0] : 0.f;
    }

    // main loop: A epochs 0..255 (steps 8m..8m+7, publishes u(8m-1..8m+6));
    //            B epochs 1..256 (j = 8m-9..8m-2, all u's already published).
    for (int m = 0; m <= 256; ++m) {
        if (isA) {
            if (m <= 255) {
                const int mn = (m + 1 <= 255) ? m + 1 : 255;
                const float4 xn0 = *(const float4*)(xrow + 8 * mn);
                const float4 xn1 = *(const float4*)(xrow + 8 * mn + 4);
                const float xs[8] = {xa.x, xa.y, xa.z, xa.w,
                                     xb.x, xb.y, xb.z, xb.w};
                const int sb = (m & 1) * 8;
                #pragma unroll
                for (int k = 0; k < 8; ++k) {
                    // h0(i) = tanh(x(i)*wih0 + Whh0 . h0(i-1) + b0)
                    f2 ac; PKDOT(ac, W0, H0);
                    const float s0 = fmaf(xs[k], wih0i, b0c);
                    hown = fast_tanh((s0 + ac.x) + ac.y);
                    h0b[lane] = f2bf(hown);
                    __builtin_amdgcn_wave_barrier();
                    const uint4    rb = *(const uint4*)h0b;        // units 0..7
                    const unsigned rc = *(const unsigned*)(h0b + 8); // 8,9
                    // u(i-1) on OLD H0 (covers readback latency)
                    f2 uc; PKDOT(uc, W1, H0);
                    up[((sb + k + 15) & 15) * 16] = (ub + uc.x) + uc.y;
                    H0[0] = unpk(rb.x); H0[1] = unpk(rb.y);
                    H0[2] = unpk(rb.z); H0[3] = unpk(rb.w);
                    H0[4] = unpk(rc);
                }
                xa = xn0; xb = xn1;
            }
        } else {
            if (m >= 1) {
                const int bb = (m & 1) ? 15 : 7;   // first slot of this epoch
                float u[8];
                #pragma unroll
                for (int k = 0; k < 8; ++k)
                    u[k] = up[((bb + k) & 15) * 16];
                float c[8];
                #pragma unroll
                for (int k = 0; k < 8; ++k) {
                    // j = 8m-9+k; h1(j) = tanh(u(j) + Whh1 . h1(j-1))
                    f2 ac; PKDOT(ac, W2, H1);
                    const float s1 = (u[k] + ac.x) + ac.y;  // lane10: out(j-1)
                    c[k] = s1;
                    const float hn = fast_tanh(s1);
                    h1b[lane] = f2bf(hn);
                    __builtin_amdgcn_wave_barrier();
                    const uint4    qb = *(const uint4*)h1b;
                    const unsigned qc = *(const unsigned*)(h1b + 8);
                    if (k > 0 || m > 1) {     // mask j = -1 (m=1, k=0)
                        H1[0] = unpk(qb.x); H1[1] = unpk(qb.y);
                        H1[2] = unpk(qb.z); H1[3] = unpk(qb.w);
                        H1[4] = unpk(qc);
                    }
                }
                // c[k] = out(8m-10+k); quads with 2-value carry
                if (ol) {
                    if (m == 1) {
                        *(float4*)(orow) = make_float4(c[2], c[3], c[4], c[5]);
                    } else {
                        *(float4*)(orow + 8*m - 12) = make_float4(P1, P2, c[0], c[1]);
                        *(float4*)(orow + 8*m - 8)  = make_float4(c[2], c[3], c[4], c[5]);
                    }
                }
                P1 = c[6]; P2 = c[7];
            }
        }
        __syncthreads();
    }

    // ---- tail: u(2047) publish by A, then B computes h1(2047) + out ----
    if (isA) {
        f2 uc; PKDOT(uc, W1, H0);                // H0 = h0(2047)
        up[15 * 16] = (ub + uc.x) + uc.y;        // slot 2047 & 15 = 15
    }
    __syncthreads();
    if (!isA) {
        const float u47 = up[15 * 16];
        f2 ac; PKDOT(ac, W2, H1);                // H1 = h1(2046)
        const float sA = (u47 + ac.x) + ac.y;    // lane10: out(2046)
        const float h1f = fast_tanh(sA);
        h1b[lane] = f2bf(h1f);
        __builtin_amdgcn_wave_barrier();
        const uint4    qb = *(const uint4*)h1b;
        const unsigned qc = *(const unsigned*)(h1b + 8);
        H1[0] = unpk(qb.x); H1[1] = unpk(qb.y);
        H1[2] = unpk(qb.z); H1[3] = unpk(qb.w);
        H1[4] = unpk(qc);                        // h1(2047)
        f2 a2; PKDOT(a2, W2, H1);
        const float o47 = (obias + a2.x) + a2.y; // lane10: out(2047)
        if (ol)
            *(float4*)(orow + TT - 4) = make_float4(P1, P2, sA, o47);
        if (act)
            out[(size_t)BB*TT + (size_t)BB*HID + (size_t)row*HID + lane] = h1f;
    } else {
        if (act)
            out[(size_t)BB*TT + (size_t)row*HID + lane] = hown;   // h0(2047)
    }
}

extern "C" void kernel_launch(void* const* d_in, const int* in_sizes, int n_in,
                              void* d_out, int out_size, void* d_ws, size_t ws_size,
                              hipStream_t stream) {
    const float* x    = (const float*)d_in[0];
    const float* hs   = (const float*)d_in[1];
    const float* Wih0 = (const float*)d_in[2];
    const float* Whh0 = (const float*)d_in[3];
    const float* bih0 = (const float*)d_in[4];
    const float* bhh0 = (const float*)d_in[5];
    const float* Wih1 = (const float*)d_in[6];
    const float* Whh1 = (const float*)d_in[7];
    const float* bih1 = (const float*)d_in[8];
    const float* bhh1 = (const float*)d_in[9];
    const float* Wout = (const float*)d_in[10];
    const float* bout = (const float*)d_in[11];
    float* out = (float*)d_out;

    dim3 grid(BB / 4), block(128);
    hipLaunchKernelGGL(rnn_kernel, grid, block, 0, stream,
        x, hs, Wih0, Whh0, bih0, bhh0, Wih1, Whh1, bih1, bhh1, Wout, bout, out);
}